// Round 11
// baseline (129.959 us; speedup 1.0000x reference)
//
#include <hip/hip_runtime.h>

typedef _Float16 f16;
typedef _Float16 f16x2 __attribute__((ext_vector_type(2)));
typedef _Float16 f16x4 __attribute__((ext_vector_type(4)));
typedef _Float16 f16x8 __attribute__((ext_vector_type(8)));
typedef float f32x4 __attribute__((ext_vector_type(4)));
typedef float f32x16 __attribute__((ext_vector_type(16)));
typedef unsigned int u32;
typedef unsigned int u32x4 __attribute__((ext_vector_type(4)));

__device__ inline f32x16 mfma32(f16x8 a, f16x8 b, f32x16 c) {
    return __builtin_amdgcn_mfma_f32_32x32x16_f16(a, b, c, 0, 0, 0);
}

__device__ inline u32 pk2u(float a, float b) {
    return __builtin_bit_cast(u32, __builtin_amdgcn_cvt_pkrtz(a, b));
}

// 8B-granular LDS helpers (rows padded to 68 f16 = 136 B: only 8B-aligned)
__device__ inline void st8(f16* p, f16x8 v) {
    *(f16x4*)p = __builtin_shufflevector(v, v, 0, 1, 2, 3);
    *(f16x4*)(p + 4) = __builtin_shufflevector(v, v, 4, 5, 6, 7);
}
__device__ inline f16x8 ld8(const f16* p) {
    f16x4 lo = *(const f16x4*)p;
    f16x4 hi = *(const f16x4*)(p + 4);
    return __builtin_shufflevector(lo, hi, 0, 1, 2, 3, 4, 5, 6, 7);
}

// ---------------------------------------------------------------------------
// Kernel 1: merged prep. blocks [0,1536): weight norm -> w f16.
//   blocks [1536, 2560): transpose x (B,C,N) fp32 -> xT (B,N,C) f16.
//   Transpose: 128c x 32n tiles; loads 128B-coalesced f32, stores f16x4
//   (256B per 32-lane phase; R10's 32x32 tiles had half-rate f16 stores).
// ---------------------------------------------------------------------------
__global__ __launch_bounds__(256) void prep_k(const float* __restrict__ pv,
                                              const float* __restrict__ pg,
                                              f16* __restrict__ w,
                                              const float* __restrict__ x,
                                              f16* __restrict__ xT) {
    int bid = blockIdx.x;
    if (bid < 1536) {
        int o = bid;
        const float* row = pv + (size_t)o * 512;
        float s = 0.f;
        for (int c = threadIdx.x; c < 512; c += 256) { float t = row[c]; s += t * t; }
        for (int off = 32; off; off >>= 1) s += __shfl_down(s, off, 64);
        __shared__ float red[4];
        int lane = threadIdx.x & 63, wid = threadIdx.x >> 6;
        if (lane == 0) red[wid] = s;
        __syncthreads();
        float tot = red[0] + red[1] + red[2] + red[3];
        float scale = pg[o] * rsqrtf(tot);
        for (int c = threadIdx.x; c < 512; c += 256)
            w[(size_t)o * 512 + c] = (f16)(row[c] * scale);
    } else {
        int t2 = bid - 1536;                 // 0..1023
        int n0 = (t2 & 31) * 32;             // 32 n-tiles
        int c0 = ((t2 >> 5) & 3) * 128;      // 4 c-tiles
        int b  = t2 >> 7;                    // 8 batches
        __shared__ float t[128][33];         // 4-way LDS conflict on read: ok
        const float* xb = x + (size_t)b * 512 * 1024;
        int tx = threadIdx.x & 31, trow = threadIdx.x >> 5;  // 32 x 8
        for (int p = 0; p < 16; p++)
            t[trow + 8 * p][tx] = xb[(size_t)(c0 + trow + 8 * p) * 1024 + n0 + tx];
        __syncthreads();
        f16* xTb = xT + (size_t)b * 1024 * 512;
        for (int p = 0; p < 4; p++) {
            int n = trow + 8 * p;
            int cc = tx * 4;
            f16x4 o;
            for (int j = 0; j < 4; j++) o[j] = (f16)t[cc + j][n];
            *(f16x4*)&xTb[(size_t)(n0 + n) * 512 + c0 + cc] = o;
        }
    }
}

// ---------------------------------------------------------------------------
// Kernel 3: QKV GEMM, 32x32x16 MFMA core, single-buffer BK=64 + register
//   prefetch, XOR-swizzled unpadded LDS (frozen: R8-R10 state).
// ---------------------------------------------------------------------------
__global__ __launch_bounds__(256) void qkv_gemm_k(const f16* __restrict__ w,
                                                  const f16* __restrict__ xT,
                                                  const float* __restrict__ pb,
                                                  f16* __restrict__ qk,
                                                  f16* __restrict__ v) {
    __shared__ f16 lA[128 * 64];   // 16 KB
    __shared__ f16 lB[128 * 64];   // 16 KB
    int b = blockIdx.z;
    int oBase = blockIdx.y * 128;
    int nBase = blockIdx.x * 128;
    const f16* xb = xT + (size_t)b * 1024 * 512;
    int tid = threadIdx.x, lane = tid & 63, warp = tid >> 6;
    int wy = warp >> 1, wx = warp & 1;
    int l31 = lane & 31, hi = lane >> 5;

    int srow = lane >> 3;
    int phys = lane & 7;
    int schunk = phys ^ srow;
    const f16* aS[4]; const f16* bS[4]; int ldsOff[4];
    for (int j = 0; j < 4; j++) {
        int rb = (warp * 4 + j) * 8;
        aS[j] = w  + (size_t)(oBase + rb + srow) * 512 + schunk * 8;
        bS[j] = xb + (size_t)(nBase + rb + srow) * 512 + schunk * 8;
        ldsOff[j] = (rb + srow) * 64 + phys * 8;
    }
    int phk[4];
    for (int ks = 0; ks < 4; ks++)
        phk[ks] = (((ks * 2 + hi) ^ (l31 & 7))) * 8;

    f16x8 rA[4], rB[4];
    for (int j = 0; j < 4; j++) {
        rA[j] = *(const f16x8*)aS[j];
        rB[j] = *(const f16x8*)bS[j];
    }

    f32x16 acc[2][2] = {};

    for (int i = 0; i < 8; i++) {
        __syncthreads();
        for (int j = 0; j < 4; j++) {
            *(f16x8*)&lA[ldsOff[j]] = rA[j];
            *(f16x8*)&lB[ldsOff[j]] = rB[j];
        }
        __syncthreads();
        if (i < 7) {
            int k0 = (i + 1) * 64;
            for (int j = 0; j < 4; j++) {
                rA[j] = *(const f16x8*)(aS[j] + k0);
                rB[j] = *(const f16x8*)(bS[j] + k0);
            }
        }
        for (int ks = 0; ks < 4; ks++) {
            f16x8 af[2], bf[2];
            for (int mi = 0; mi < 2; mi++)
                af[mi] = *(f16x8*)&lA[(wy * 64 + mi * 32 + l31) * 64 + phk[ks]];
            for (int ni = 0; ni < 2; ni++)
                bf[ni] = *(f16x8*)&lB[(wx * 64 + ni * 32 + l31) * 64 + phk[ks]];
            for (int mi = 0; mi < 2; mi++)
                for (int ni = 0; ni < 2; ni++)
                    acc[mi][ni] = mfma32(af[mi], bf[ni], acc[mi][ni]);
        }
    }

    int selB = oBase >> 9;
    for (int mi = 0; mi < 2; mi++) {
        for (int g = 0; g < 4; g++) {
            int oR = oBase + wy * 64 + mi * 32 + 8 * g + 4 * hi;
            int h = (oR >> 6) & 7, d0 = oR & 63;
            for (int ni = 0; ni < 2; ni++) {
                int n = nBase + wx * 64 + ni * 32 + l31;
                if (selB < 2) {
                    float sc = selB == 0 ? 0.125f : 1.0f;  // fold 1/sqrt(64)
                    f16x4 o4;
                    for (int r = 0; r < 4; r++)
                        o4[r] = (f16)((acc[mi][ni][g * 4 + r] + pb[oR + r]) * sc);
                    *(f16x4*)&qk[((((size_t)b * 2 + selB) * 8 + h) * 1024 + n) * 64 + d0] = o4;
                } else {
                    for (int r = 0; r < 4; r++) {
                        float val = acc[mi][ni][g * 4 + r] + pb[oR + r];
                        v[(((size_t)b * 8 + h) * 64 + d0 + r) * 1024 + n] = (f16)val;
                    }
                }
            }
        }
    }
}

// ---------------------------------------------------------------------------
// Kernel 4: fused attention + residual. 32x32x16 core, wave owns 32 q,
//   block = 128 q (4 waves), flat grid 512 with XCD-aware swizzle:
//   consecutive blockIdx round-robin across the 8 XCDs, so we pin each
//   bh-group (its 8 qBase blocks) to ONE XCD -> K/V tiles stay in that
//   XCD's 4 MB L2 (8 heads x 256 KB = 2 MB) instead of being re-fetched
//   by all 8 XCDs (R5 attn FETCH was 78 MB vs ~42 ideal).
//   P in registers; PV B-frag via shfl_xor(32) pair per ks; no online max.
// ---------------------------------------------------------------------------
#define ALDK 68
__global__ __launch_bounds__(256, 2) void attn_k(const f16* __restrict__ qk,
                                                 const f16* __restrict__ vg,
                                                 const float* __restrict__ x,
                                                 float* __restrict__ out) {
    __shared__ __align__(16) f16 smem[2 * 64 * ALDK];
    f16* lK = smem;
    f16* lV = smem + 64 * ALDK;

    int g = blockIdx.x;                 // 0..511
    int xcd = g & 7, idx = g >> 3;      // blocks g=xcd (mod 8) land on XCD xcd
    int bh = xcd * 8 + (idx & 7);       // 8 bh-groups per XCD
    int qBase = (idx >> 3) * 128;       // 8 q-tiles per bh, same XCD
    int b = bh >> 3, h = bh & 7;
    int tid = threadIdx.x, lane = tid & 63, warp = tid >> 6;
    int l31 = lane & 31, hi = lane >> 5;

    const f16* qbase = qk + (((size_t)b * 2 + 0) * 8 + h) * 1024 * 64;
    const f16* kbase = qk + (((size_t)b * 2 + 1) * 8 + h) * 1024 * 64;
    const f16* vbase = vg + ((size_t)b * 8 + h) * 64 * 1024;

    int q0 = qBase + warp * 32;
    f16x8 aq[4];
    for (int ks = 0; ks < 4; ks++)
        aq[ks] = *(const f16x8*)&qbase[(size_t)(q0 + l31) * 64 + ks * 16 + hi * 8];

    int sr0 = tid >> 3, sc0 = (tid & 7) * 8;
    int sr1 = sr0 + 32;

    f16x8 rK[2], rV[2];
    rK[0] = *(const f16x8*)&kbase[(size_t)sr0 * 64 + sc0];
    rK[1] = *(const f16x8*)&kbase[(size_t)sr1 * 64 + sc0];
    rV[0] = *(const f16x8*)&vbase[(size_t)sr0 * 1024 + sc0];
    rV[1] = *(const f16x8*)&vbase[(size_t)sr1 * 1024 + sc0];

    f32x16 accO[2] = {};
    float l_acc = 0.f;

    for (int kt = 0; kt < 16; kt++) {
        __syncthreads();
        st8(&lK[sr0 * ALDK + sc0], rK[0]);
        st8(&lK[sr1 * ALDK + sc0], rK[1]);
        st8(&lV[sr0 * ALDK + sc0], rV[0]);
        st8(&lV[sr1 * ALDK + sc0], rV[1]);
        __syncthreads();
        if (kt < 15) {
            const f16* kb = kbase + (size_t)(kt + 1) * 64 * 64;
            rK[0] = *(const f16x8*)&kb[(size_t)sr0 * 64 + sc0];
            rK[1] = *(const f16x8*)&kb[(size_t)sr1 * 64 + sc0];
            rV[0] = *(const f16x8*)&vbase[(size_t)sr0 * 1024 + (kt + 1) * 64 + sc0];
            rV[1] = *(const f16x8*)&vbase[(size_t)sr1 * 1024 + (kt + 1) * 64 + sc0];
        }

        // S^T per mt; p = exp(s) packed to f16x2 pairs in registers:
        // P0[mt][g] = k-pair {8g+4hi+0,1}, P1 = {8g+4hi+2,3} (col q = l31)
        u32 P0[2][4], P1[2][4];
        float rs = 0.f;
        for (int mt = 0; mt < 2; mt++) {
            f16x8 ak[4];
            for (int ks = 0; ks < 4; ks++)
                ak[ks] = ld8(&lK[(mt * 32 + l31) * ALDK + ks * 16 + hi * 8]);
            f32x16 stt = {};
            for (int ks = 0; ks < 4; ks++)
                stt = mfma32(ak[ks], aq[ks], stt);
            for (int gg = 0; gg < 4; gg++) {
                float p0 = __expf(stt[gg * 4 + 0]);
                float p1 = __expf(stt[gg * 4 + 1]);
                float p2 = __expf(stt[gg * 4 + 2]);
                float p3 = __expf(stt[gg * 4 + 3]);
                rs += (p0 + p1) + (p2 + p3);
                P0[mt][gg] = pk2u(p0, p1);
                P1[mt][gg] = pk2u(p2, p3);
            }
        }
        l_acc += rs;

        // PV: B-frag for ks: mt=ks>>1; j0-3 from lane (q,0), j4-7 from (q,1),
        // both with g = 2(ks&1)+hi_dest.  Send g = 2(ks&1)+(hi^1).
        f16x8 av[2][4];
        for (int dt = 0; dt < 2; dt++)
            for (int ks = 0; ks < 4; ks++)
                av[dt][ks] = ld8(&lV[(dt * 32 + l31) * ALDK + ks * 16 + hi * 8]);
        f16x8 bfrag[4];
        for (int ks = 0; ks < 4; ks++) {
            int mt = ks >> 1, ge = 2 * (ks & 1);
            u32 e00 = P0[mt][ge], e01 = P0[mt][ge + 1];
            u32 e10 = P1[mt][ge], e11 = P1[mt][ge + 1];
            u32 k0 = hi ? e01 : e00;       // keep: g = ge + hi
            u32 k1 = hi ? e11 : e10;
            u32 s0 = hi ? e00 : e01;       // send: g = ge + (hi^1)
            u32 s1 = hi ? e10 : e11;
            u32 r0 = __shfl_xor(s0, 32, 64);
            u32 r1 = __shfl_xor(s1, 32, 64);
            u32 a0 = hi ? r0 : k0, a1 = hi ? r1 : k1;   // from (q,0)
            u32 b0 = hi ? k0 : r0, b1 = hi ? k1 : r1;   // from (q,1)
            u32x4 t = {a0, a1, b0, b1};
            bfrag[ks] = __builtin_bit_cast(f16x8, t);
        }
        for (int dt = 0; dt < 2; dt++)
            for (int ks = 0; ks < 4; ks++)
                accO[dt] = mfma32(av[dt][ks], bfrag[ks], accO[dt]);
    }

    // epilogue: l = own + partner halves; direct 2-segment coalesced stores
    float lt = l_acc + __shfl_xor(l_acc, 32, 64);
    float rl = 1.0f / lt;
    int q = q0 + l31;
    for (int dt = 0; dt < 2; dt++)
        for (int gg = 0; gg < 4; gg++)
            for (int r = 0; r < 4; r++) {
                int d = dt * 32 + 8 * gg + 4 * hi + r;
                size_t gi = ((size_t)b * 512 + h * 64 + d) * 1024 + q;
                out[gi] = x[gi] + accO[dt][gg * 4 + r] * rl;
            }
}

// ---------------------------------------------------------------------------
extern "C" void kernel_launch(void* const* d_in, const int* in_sizes, int n_in,
                              void* d_out, int out_size, void* d_ws, size_t ws_size,
                              hipStream_t stream) {
    (void)in_sizes; (void)n_in; (void)out_size; (void)ws_size;
    const float* x  = (const float*)d_in[0];
    const float* pv = (const float*)d_in[1];
    const float* pg = (const float*)d_in[2];
    const float* pb = (const float*)d_in[3];
    float* out = (float*)d_out;

    char* ws = (char*)d_ws;
    f16* w   = (f16*)(ws);                                   // 1,572,864 B
    f16* xT  = (f16*)(ws + 1572864);                         // 8,388,608 B
    f16* qk  = (f16*)(ws + 1572864 + 8388608);               // 16,777,216 B
    f16* v   = (f16*)(ws + 1572864 + 8388608 + 16777216);    // 8,388,608 B

    hipLaunchKernelGGL(prep_k,     dim3(2560),     dim3(256), 0, stream, pv, pg, w, x, xT);
    hipLaunchKernelGGL(qkv_gemm_k, dim3(8, 12, 8), dim3(256), 0, stream, w, xT, pb, qk, v);
    hipLaunchKernelGGL(attn_k,     dim3(512),      dim3(256), 0, stream, qk, v, x, out);
}

// Round 12
// 129.661 us; speedup vs baseline: 1.0023x; 1.0023x over previous
//
#include <hip/hip_runtime.h>

typedef _Float16 f16;
typedef _Float16 f16x2 __attribute__((ext_vector_type(2)));
typedef _Float16 f16x4 __attribute__((ext_vector_type(4)));
typedef _Float16 f16x8 __attribute__((ext_vector_type(8)));
typedef float f32x4 __attribute__((ext_vector_type(4)));
typedef float f32x16 __attribute__((ext_vector_type(16)));
typedef unsigned int u32;
typedef unsigned int u32x4 __attribute__((ext_vector_type(4)));

__device__ inline f32x16 mfma32(f16x8 a, f16x8 b, f32x16 c) {
    return __builtin_amdgcn_mfma_f32_32x32x16_f16(a, b, c, 0, 0, 0);
}

__device__ inline u32 pk2u(float a, float b) {
    return __builtin_bit_cast(u32, __builtin_amdgcn_cvt_pkrtz(a, b));
}

// 8B-granular LDS helpers (rows padded to 68 f16 = 136 B: only 8B-aligned)
__device__ inline void st8(f16* p, f16x8 v) {
    *(f16x4*)p = __builtin_shufflevector(v, v, 0, 1, 2, 3);
    *(f16x4*)(p + 4) = __builtin_shufflevector(v, v, 4, 5, 6, 7);
}
__device__ inline f16x8 ld8(const f16* p) {
    f16x4 lo = *(const f16x4*)p;
    f16x4 hi = *(const f16x4*)(p + 4);
    return __builtin_shufflevector(lo, hi, 0, 1, 2, 3, 4, 5, 6, 7);
}

// ---------------------------------------------------------------------------
// Kernel 1: merged prep. blocks [0,1536): weight norm -> w f16.
//           blocks [1536, 5632): transpose x (B,C,N) fp32 -> xT (B,N,C) f16.
//   (R10 state: 32x32 tiles, 33-pitch f32 LDS — measured-good; the R11
//    128x33 variant had 4-way read aliasing and regressed.)
// ---------------------------------------------------------------------------
__global__ __launch_bounds__(256) void prep_k(const float* __restrict__ pv,
                                              const float* __restrict__ pg,
                                              f16* __restrict__ w,
                                              const float* __restrict__ x,
                                              f16* __restrict__ xT) {
    int bid = blockIdx.x;
    if (bid < 1536) {
        int o = bid;
        const float* row = pv + (size_t)o * 512;
        float s = 0.f;
        for (int c = threadIdx.x; c < 512; c += 256) { float t = row[c]; s += t * t; }
        for (int off = 32; off; off >>= 1) s += __shfl_down(s, off, 64);
        __shared__ float red[4];
        int lane = threadIdx.x & 63, wid = threadIdx.x >> 6;
        if (lane == 0) red[wid] = s;
        __syncthreads();
        float tot = red[0] + red[1] + red[2] + red[3];
        float scale = pg[o] * rsqrtf(tot);
        for (int c = threadIdx.x; c < 512; c += 256)
            w[(size_t)o * 512 + c] = (f16)(row[c] * scale);
    } else {
        int t2 = bid - 1536;
        int n0 = (t2 & 31) * 32, c0 = ((t2 >> 5) & 15) * 32, b = t2 >> 9;
        int tx = threadIdx.x & 31, ty = threadIdx.x >> 5;  // 32 x 8
        __shared__ float t[32][33];
        const float* xb = x + (size_t)b * 512 * 1024;
        for (int i = 0; i < 4; i++)
            t[ty + 8 * i][tx] = xb[(size_t)(c0 + ty + 8 * i) * 1024 + n0 + tx];
        __syncthreads();
        f16* xTb = xT + (size_t)b * 1024 * 512;
        for (int i = 0; i < 4; i++)
            xTb[(size_t)(n0 + ty + 8 * i) * 512 + c0 + tx] = (f16)t[tx][ty + 8 * i];
    }
}

// ---------------------------------------------------------------------------
// Kernel 3: QKV GEMM, 32x32x16 MFMA core, single-buffer BK=64 + register
//   prefetch, XOR-swizzled unpadded LDS (frozen: R8-R10 state).
// ---------------------------------------------------------------------------
__global__ __launch_bounds__(256) void qkv_gemm_k(const f16* __restrict__ w,
                                                  const f16* __restrict__ xT,
                                                  const float* __restrict__ pb,
                                                  f16* __restrict__ qk,
                                                  f16* __restrict__ v) {
    __shared__ f16 lA[128 * 64];   // 16 KB
    __shared__ f16 lB[128 * 64];   // 16 KB
    int b = blockIdx.z;
    int oBase = blockIdx.y * 128;
    int nBase = blockIdx.x * 128;
    const f16* xb = xT + (size_t)b * 1024 * 512;
    int tid = threadIdx.x, lane = tid & 63, warp = tid >> 6;
    int wy = warp >> 1, wx = warp & 1;
    int l31 = lane & 31, hi = lane >> 5;

    int srow = lane >> 3;
    int phys = lane & 7;
    int schunk = phys ^ srow;
    const f16* aS[4]; const f16* bS[4]; int ldsOff[4];
    for (int j = 0; j < 4; j++) {
        int rb = (warp * 4 + j) * 8;
        aS[j] = w  + (size_t)(oBase + rb + srow) * 512 + schunk * 8;
        bS[j] = xb + (size_t)(nBase + rb + srow) * 512 + schunk * 8;
        ldsOff[j] = (rb + srow) * 64 + phys * 8;
    }
    int phk[4];
    for (int ks = 0; ks < 4; ks++)
        phk[ks] = (((ks * 2 + hi) ^ (l31 & 7))) * 8;

    f16x8 rA[4], rB[4];
    for (int j = 0; j < 4; j++) {
        rA[j] = *(const f16x8*)aS[j];
        rB[j] = *(const f16x8*)bS[j];
    }

    f32x16 acc[2][2] = {};

    for (int i = 0; i < 8; i++) {
        __syncthreads();
        for (int j = 0; j < 4; j++) {
            *(f16x8*)&lA[ldsOff[j]] = rA[j];
            *(f16x8*)&lB[ldsOff[j]] = rB[j];
        }
        __syncthreads();
        if (i < 7) {
            int k0 = (i + 1) * 64;
            for (int j = 0; j < 4; j++) {
                rA[j] = *(const f16x8*)(aS[j] + k0);
                rB[j] = *(const f16x8*)(bS[j] + k0);
            }
        }
        for (int ks = 0; ks < 4; ks++) {
            f16x8 af[2], bf[2];
            for (int mi = 0; mi < 2; mi++)
                af[mi] = *(f16x8*)&lA[(wy * 64 + mi * 32 + l31) * 64 + phk[ks]];
            for (int ni = 0; ni < 2; ni++)
                bf[ni] = *(f16x8*)&lB[(wx * 64 + ni * 32 + l31) * 64 + phk[ks]];
            for (int mi = 0; mi < 2; mi++)
                for (int ni = 0; ni < 2; ni++)
                    acc[mi][ni] = mfma32(af[mi], bf[ni], acc[mi][ni]);
        }
    }

    int selB = oBase >> 9;
    for (int mi = 0; mi < 2; mi++) {
        for (int g = 0; g < 4; g++) {
            int oR = oBase + wy * 64 + mi * 32 + 8 * g + 4 * hi;
            int h = (oR >> 6) & 7, d0 = oR & 63;
            for (int ni = 0; ni < 2; ni++) {
                int n = nBase + wx * 64 + ni * 32 + l31;
                if (selB < 2) {
                    float sc = selB == 0 ? 0.125f : 1.0f;  // fold 1/sqrt(64)
                    f16x4 o4;
                    for (int r = 0; r < 4; r++)
                        o4[r] = (f16)((acc[mi][ni][g * 4 + r] + pb[oR + r]) * sc);
                    *(f16x4*)&qk[((((size_t)b * 2 + selB) * 8 + h) * 1024 + n) * 64 + d0] = o4;
                } else {
                    for (int r = 0; r < 4; r++) {
                        float val = acc[mi][ni][g * 4 + r] + pb[oR + r];
                        v[(((size_t)b * 8 + h) * 64 + d0 + r) * 1024 + n] = (f16)val;
                    }
                }
            }
        }
    }
}

// ---------------------------------------------------------------------------
// Kernel 4: fused attention + residual (R10 state: plain grid, no XCD
//   swizzle — the R11 swizzle rested on an unverified blockIdx->XCD mapping
//   and regressed).  32x32x16 core, wave owns 32 q, block = 128 q, grid
//   8 x 64 = 512 = 2 blocks/CU.  P in registers; PV B-frag via one
//   shfl_xor(32) pair per ks; no online max; l reduced at epilogue.
// ---------------------------------------------------------------------------
#define ALDK 68
__global__ __launch_bounds__(256, 2) void attn_k(const f16* __restrict__ qk,
                                                 const f16* __restrict__ vg,
                                                 const float* __restrict__ x,
                                                 float* __restrict__ out) {
    __shared__ __align__(16) f16 smem[2 * 64 * ALDK];
    f16* lK = smem;
    f16* lV = smem + 64 * ALDK;

    int bh = blockIdx.y;
    int b = bh >> 3, h = bh & 7;
    int qBase = blockIdx.x * 128;
    int tid = threadIdx.x, lane = tid & 63, warp = tid >> 6;
    int l31 = lane & 31, hi = lane >> 5;

    const f16* qbase = qk + (((size_t)b * 2 + 0) * 8 + h) * 1024 * 64;
    const f16* kbase = qk + (((size_t)b * 2 + 1) * 8 + h) * 1024 * 64;
    const f16* vbase = vg + ((size_t)b * 8 + h) * 64 * 1024;

    int q0 = qBase + warp * 32;
    f16x8 aq[4];
    for (int ks = 0; ks < 4; ks++)
        aq[ks] = *(const f16x8*)&qbase[(size_t)(q0 + l31) * 64 + ks * 16 + hi * 8];

    int sr0 = tid >> 3, sc0 = (tid & 7) * 8;
    int sr1 = sr0 + 32;

    f16x8 rK[2], rV[2];
    rK[0] = *(const f16x8*)&kbase[(size_t)sr0 * 64 + sc0];
    rK[1] = *(const f16x8*)&kbase[(size_t)sr1 * 64 + sc0];
    rV[0] = *(const f16x8*)&vbase[(size_t)sr0 * 1024 + sc0];
    rV[1] = *(const f16x8*)&vbase[(size_t)sr1 * 1024 + sc0];

    f32x16 accO[2] = {};
    float l_acc = 0.f;

    for (int kt = 0; kt < 16; kt++) {
        __syncthreads();
        st8(&lK[sr0 * ALDK + sc0], rK[0]);
        st8(&lK[sr1 * ALDK + sc0], rK[1]);
        st8(&lV[sr0 * ALDK + sc0], rV[0]);
        st8(&lV[sr1 * ALDK + sc0], rV[1]);
        __syncthreads();
        if (kt < 15) {
            const f16* kb = kbase + (size_t)(kt + 1) * 64 * 64;
            rK[0] = *(const f16x8*)&kb[(size_t)sr0 * 64 + sc0];
            rK[1] = *(const f16x8*)&kb[(size_t)sr1 * 64 + sc0];
            rV[0] = *(const f16x8*)&vbase[(size_t)sr0 * 1024 + (kt + 1) * 64 + sc0];
            rV[1] = *(const f16x8*)&vbase[(size_t)sr1 * 1024 + (kt + 1) * 64 + sc0];
        }

        // S^T per mt; p = exp(s) packed to f16x2 pairs in registers:
        // P0[mt][g] = k-pair {8g+4hi+0,1}, P1 = {8g+4hi+2,3} (col q = l31)
        u32 P0[2][4], P1[2][4];
        float rs = 0.f;
        for (int mt = 0; mt < 2; mt++) {
            f16x8 ak[4];
            for (int ks = 0; ks < 4; ks++)
                ak[ks] = ld8(&lK[(mt * 32 + l31) * ALDK + ks * 16 + hi * 8]);
            f32x16 stt = {};
            for (int ks = 0; ks < 4; ks++)
                stt = mfma32(ak[ks], aq[ks], stt);
            for (int g = 0; g < 4; g++) {
                float p0 = __expf(stt[g * 4 + 0]);
                float p1 = __expf(stt[g * 4 + 1]);
                float p2 = __expf(stt[g * 4 + 2]);
                float p3 = __expf(stt[g * 4 + 3]);
                rs += (p0 + p1) + (p2 + p3);
                P0[mt][g] = pk2u(p0, p1);
                P1[mt][g] = pk2u(p2, p3);
            }
        }
        l_acc += rs;

        // PV: B-frag for ks: mt=ks>>1; j0-3 from lane (q,0), j4-7 from (q,1),
        // both with g = 2(ks&1)+hi_dest.  Send g = 2(ks&1)+(hi^1).
        f16x8 av[2][4];
        for (int dt = 0; dt < 2; dt++)
            for (int ks = 0; ks < 4; ks++)
                av[dt][ks] = ld8(&lV[(dt * 32 + l31) * ALDK + ks * 16 + hi * 8]);
        f16x8 bfrag[4];
        for (int ks = 0; ks < 4; ks++) {
            int mt = ks >> 1, ge = 2 * (ks & 1);
            u32 e00 = P0[mt][ge], e01 = P0[mt][ge + 1];
            u32 e10 = P1[mt][ge], e11 = P1[mt][ge + 1];
            u32 k0 = hi ? e01 : e00;       // keep: g = ge + hi
            u32 k1 = hi ? e11 : e10;
            u32 s0 = hi ? e00 : e01;       // send: g = ge + (hi^1)
            u32 s1 = hi ? e10 : e11;
            u32 r0 = __shfl_xor(s0, 32, 64);
            u32 r1 = __shfl_xor(s1, 32, 64);
            u32 a0 = hi ? r0 : k0, a1 = hi ? r1 : k1;   // from (q,0)
            u32 b0 = hi ? k0 : r0, b1 = hi ? k1 : r1;   // from (q,1)
            u32x4 t = {a0, a1, b0, b1};
            bfrag[ks] = __builtin_bit_cast(f16x8, t);
        }
        for (int dt = 0; dt < 2; dt++)
            for (int ks = 0; ks < 4; ks++)
                accO[dt] = mfma32(av[dt][ks], bfrag[ks], accO[dt]);
    }

    // epilogue: l = own + partner halves; direct 2-segment coalesced stores
    float lt = l_acc + __shfl_xor(l_acc, 32, 64);
    float rl = 1.0f / lt;
    int q = q0 + l31;
    for (int dt = 0; dt < 2; dt++)
        for (int g = 0; g < 4; g++)
            for (int r = 0; r < 4; r++) {
                int d = dt * 32 + 8 * g + 4 * hi + r;
                size_t gi = ((size_t)b * 512 + h * 64 + d) * 1024 + q;
                out[gi] = x[gi] + accO[dt][g * 4 + r] * rl;
            }
}

// ---------------------------------------------------------------------------
extern "C" void kernel_launch(void* const* d_in, const int* in_sizes, int n_in,
                              void* d_out, int out_size, void* d_ws, size_t ws_size,
                              hipStream_t stream) {
    (void)in_sizes; (void)n_in; (void)out_size; (void)ws_size;
    const float* x  = (const float*)d_in[0];
    const float* pv = (const float*)d_in[1];
    const float* pg = (const float*)d_in[2];
    const float* pb = (const float*)d_in[3];
    float* out = (float*)d_out;

    char* ws = (char*)d_ws;
    f16* w   = (f16*)(ws);                                   // 1,572,864 B
    f16* xT  = (f16*)(ws + 1572864);                         // 8,388,608 B
    f16* qk  = (f16*)(ws + 1572864 + 8388608);               // 16,777,216 B
    f16* v   = (f16*)(ws + 1572864 + 8388608 + 16777216);    // 8,388,608 B

    hipLaunchKernelGGL(prep_k,     dim3(5632),     dim3(256), 0, stream, pv, pg, w, x, xT);
    hipLaunchKernelGGL(qkv_gemm_k, dim3(8, 12, 8), dim3(256), 0, stream, w, xT, pb, qk, v);
    hipLaunchKernelGGL(attn_k,     dim3(8, 64),    dim3(256), 0, stream, qk, v, x, out);
}